// Round 4
// baseline (1420.860 us; speedup 1.0000x reference)
//
#include <hip/hip_runtime.h>
#include <hip/hip_bf16.h>

typedef __bf16 bf16_t;
typedef __bf16 bf16x8 __attribute__((ext_vector_type(8)));
typedef float f32x4 __attribute__((ext_vector_type(4)));

static constexpr int S_ = 2048;
static constexpr int B_ = 8;
static constexpr int D_ = 512;
static constexpr int H_ = 8;
static constexpr int HD_ = 64;
static constexpr int F_ = 2048;
static constexpr int E_ = 64;
static constexpr int NT = S_ * B_;   // 16384 tokens
static constexpr int CAP = 512;      // expert capacity = 2*NT/E
static constexpr float EPS_ = 1e-5f;

__device__ __forceinline__ float wave_sum(float v) {
#pragma unroll
  for (int m = 1; m < 64; m <<= 1) v += __shfl_xor(v, m);
  return v;
}

// async global->LDS, 16B per lane; dest = wave-uniform base + lane*16 (m97/m104)
__device__ __forceinline__ void gload_lds16(const void* g, void* l) {
  __builtin_amdgcn_global_load_lds((const __attribute__((address_space(1))) void*)g,
                                   (__attribute__((address_space(3))) void*)l, 16, 0, 0);
}

// ---------------- f32 -> bf16 convert (vectorized 8/thread) ----------------
__global__ void k_cvt(const float* __restrict__ in, bf16_t* __restrict__ out, int n8) {
  int i = blockIdx.x * blockDim.x + threadIdx.x;
  if (i >= n8) return;
  const float4* p = (const float4*)in + (size_t)i * 2;
  float4 a = p[0], b = p[1];
  bf16x8 o;
  o[0]=(bf16_t)a.x; o[1]=(bf16_t)a.y; o[2]=(bf16_t)a.z; o[3]=(bf16_t)a.w;
  o[4]=(bf16_t)b.x; o[5]=(bf16_t)b.y; o[6]=(bf16_t)b.z; o[7]=(bf16_t)b.w;
  ((bf16x8*)out)[i] = o;
}

// ------- transpose+convert: per-expert [R][C] f32 -> [C][R] bf16 (64x64 tiles) -------
__global__ void k_tcvt(const float* __restrict__ in, bf16_t* __restrict__ out,
                       int R, int C, long strideIn, long strideOut) {
  __shared__ __align__(16) float t[64][68];
  const float* ip = in + (long)blockIdx.z * strideIn;
  bf16_t* op = out + (long)blockIdx.z * strideOut;
  int r0 = blockIdx.y * 64, c0 = blockIdx.x * 64;
  int tid = threadIdx.x;
  int row = tid >> 2, cc = (tid & 3) * 16;
  const float4* g = (const float4*)(ip + (long)(r0 + row) * C + c0 + cc);
  float4 a0 = g[0], a1 = g[1], a2 = g[2], a3 = g[3];
  *(float4*)&t[row][cc + 0]  = a0;
  *(float4*)&t[row][cc + 4]  = a1;
  *(float4*)&t[row][cc + 8]  = a2;
  *(float4*)&t[row][cc + 12] = a3;
  __syncthreads();
  int oc = tid >> 2, rr = (tid & 3) * 16;
  bf16x8 o0, o1;
#pragma unroll
  for (int j = 0; j < 8; j++) o0[j] = (bf16_t)t[rr + j][oc];
#pragma unroll
  for (int j = 0; j < 8; j++) o1[j] = (bf16_t)t[rr + 8 + j][oc];
  *(bf16x8*)(op + (long)(c0 + oc) * R + r0 + rr)     = o0;
  *(bf16x8*)(op + (long)(c0 + oc) * R + r0 + rr + 8) = o1;
}

// ---------- V transpose: vT[bh][d][s] = qkv[(s*B+b)*1536 + 1024 + h*64 + d] ----------
__global__ void k_tv(const bf16_t* __restrict__ qkv, bf16_t* __restrict__ vT) {
  __shared__ __align__(16) bf16_t t[64][72];
  int bh = blockIdx.y, bI = bh >> 3, hI = bh & 7;
  int s0 = blockIdx.x * 64;
  int tid = threadIdx.x;
  int row = tid >> 2, cc = (tid & 3) * 16;
  const uint4* g = (const uint4*)(qkv + ((long)(s0 + row) * B_ + bI) * 1536 + 1024 + hI * 64 + cc);
  uint4 v0 = g[0], v1 = g[1];
  *(uint4*)&t[row][cc]     = v0;
  *(uint4*)&t[row][cc + 8] = v1;
  __syncthreads();
  int oc = tid >> 2, rr = (tid & 3) * 16;
  bf16x8 o0, o1;
#pragma unroll
  for (int j = 0; j < 8; j++) o0[j] = t[rr + j][oc];
#pragma unroll
  for (int j = 0; j < 8; j++) o1[j] = t[rr + 8 + j][oc];
  bf16_t* op = vT + ((long)bh * 64 + oc) * (long)S_ + s0 + rr;
  *(bf16x8*)(op)     = o0;
  *(bf16x8*)(op + 8) = o1;
}

// ------------- NT bf16 GEMM: C[m][n] = sum_k A[m][k]*B[n][k] + bias[n] -------------
// m97 structure: 128x128 tile, BK=32, 4 waves, global_load_lds width-16 staging
// into LINEAR [128][32] LDS (dest must be lane-linear: rule #21), 2 barriers/K-step.
template <int RELU>
__global__ __launch_bounds__(256) void k_gemm(
    const bf16_t* __restrict__ A, const bf16_t* __restrict__ Bm,
    const float* __restrict__ bias, bf16_t* __restrict__ Cout,
    int K, int lda, int ldb, int ldc,
    long aStride, long bStride, long cStride, int biasStride,
    const int* __restrict__ cnt, int mCap) {
  __shared__ __align__(16) bf16_t As[128 * 32];
  __shared__ __align__(16) bf16_t Bs[128 * 32];
  int z = blockIdx.z;
  if (cnt) {
    int c = cnt[z]; if (c > mCap) c = mCap;
    if ((int)blockIdx.y * 128 >= c) return;
  }
  long m0 = (long)blockIdx.y * 128, n0 = (long)blockIdx.x * 128;
  const bf16_t* Ab = A + (long)z * aStride + m0 * lda;
  const bf16_t* Bb = Bm + (long)z * bStride + n0 * ldb;
  int tid = threadIdx.x, wid = tid >> 6, lane = tid & 63;
  int lr = lane & 15, lg = lane >> 4;
  int wm = wid >> 1, wn = wid & 1;
  // staging map: lane l of wave w -> row w*16 + l/4 (and +64), 16B chunk l%4
  int grow = wid * 16 + (lane >> 2);
  int gcol = (lane & 3) * 8;
  const bf16_t* gA0 = Ab + (long)grow * lda + gcol;
  const bf16_t* gA1 = gA0 + (long)64 * lda;
  const bf16_t* gB0 = Bb + (long)grow * ldb + gcol;
  const bf16_t* gB1 = gB0 + (long)64 * ldb;
  bf16_t* lA0 = &As[wid * 512 + lane * 8];
  bf16_t* lA1 = lA0 + 2048;
  bf16_t* lB0 = &Bs[wid * 512 + lane * 8];
  bf16_t* lB1 = lB0 + 2048;
  f32x4 acc[4][4] = {};
  for (int k0 = 0; k0 < K; k0 += 32) {
    gload_lds16(gA0 + k0, lA0);
    gload_lds16(gA1 + k0, lA1);
    gload_lds16(gB0 + k0, lB0);
    gload_lds16(gB1 + k0, lB1);
    __syncthreads();  // drains vmcnt (gload queue) + barrier
    bf16x8 af[4], bfr[4];
#pragma unroll
    for (int i = 0; i < 4; i++) {
      af[i]  = *(const bf16x8*)&As[(wm * 64 + i * 16 + lr) * 32 + lg * 8];
      bfr[i] = *(const bf16x8*)&Bs[(wn * 64 + i * 16 + lr) * 32 + lg * 8];
    }
#pragma unroll
    for (int i = 0; i < 4; i++)
#pragma unroll
      for (int j = 0; j < 4; j++)
        acc[i][j] = __builtin_amdgcn_mfma_f32_16x16x32_bf16(af[i], bfr[j], acc[i][j], 0, 0, 0);
    __syncthreads();  // all reads done before next stage overwrites
  }
  // epilogue: C layout col=lane&15, row=(lane>>4)*4+r (m89-verified)
#pragma unroll
  for (int j = 0; j < 4; j++) {
    int col = (int)n0 + wn * 64 + j * 16 + lr;
    float bv = bias[(long)z * biasStride + col];
#pragma unroll
    for (int i = 0; i < 4; i++) {
      long row = m0 + wm * 64 + i * 16 + lg * 4;
#pragma unroll
      for (int r = 0; r < 4; r++) {
        float v = acc[i][j][r] + bv;
        if (RELU) v = fmaxf(v, 0.0f);
        Cout[(long)z * cStride + (row + r) * ldc + col] = (bf16_t)v;
      }
    }
  }
}

// ---------------- flash attention fwd: one (64-row Q tile, b, h) per block ----------------
// LP=72: row stride 144B -> ds_read_b128 bank-start (lr*4+lg*4)%32 = 2-way (free, m136).
// Softmax in exp2 domain (scale folds log2e); defer-rescale THR=8 (T13).
__global__ __launch_bounds__(256) void k_attn(const bf16_t* __restrict__ qkv,
                                              const bf16_t* __restrict__ vT,
                                              bf16_t* __restrict__ ctx) {
  constexpr int LP = 72;
  __shared__ __align__(16) bf16_t Kld[64 * LP];
  __shared__ __align__(16) bf16_t Vld[64 * LP];     // Vld[d][k]
  __shared__ __align__(16) bf16_t Pld[4][16 * LP];  // per-wave P
  int bh = blockIdx.y, bI = bh >> 3, hI = bh & 7;
  int q0 = blockIdx.x * 64;
  int tid = threadIdx.x, wid = tid >> 6, lane = tid & 63;
  int lr = lane & 15, lg = lane >> 4;
  int qrow = q0 + wid * 16 + lr;
  const bf16_t* qb = qkv + ((long)qrow * B_ + bI) * 1536 + hI * 64;
  bf16x8 qf0 = *(const bf16x8*)(qb + lg * 8);
  bf16x8 qf1 = *(const bf16x8*)(qb + 32 + lg * 8);
  f32x4 o[4] = {};
  float mrun[4], lrun[4];
#pragma unroll
  for (int r = 0; r < 4; r++) { mrun[r] = -3.0e38f; lrun[r] = 0.0f; }
  const float SC = 0.125f * 1.44269504f;  // 1/sqrt(64) * log2(e)
  int srow = tid >> 2, sc = (tid & 3) * 16;
  for (int kb = 0; kb < S_ / 64; kb++) {
    int krow = kb * 64 + srow;
    const uint4* kg = (const uint4*)(qkv + ((long)krow * B_ + bI) * 1536 + 512 + hI * 64 + sc);
    const uint4* vg = (const uint4*)(vT + ((long)bh * 64 + srow) * (long)S_ + kb * 64 + sc);
    uint4 k0v = kg[0], k1v = kg[1], v0v = vg[0], v1v = vg[1];
    __syncthreads();  // previous iteration's LDS reads done
    *(uint4*)&Kld[srow * LP + sc]     = k0v;
    *(uint4*)&Kld[srow * LP + sc + 8] = k1v;
    *(uint4*)&Vld[srow * LP + sc]     = v0v;
    *(uint4*)&Vld[srow * LP + sc + 8] = v1v;
    __syncthreads();
    // S = Q K^T (wave: 16 q-rows x 64 k-cols), exp2-domain scale
    f32x4 sacc[4] = {};
#pragma unroll
    for (int kc = 0; kc < 2; kc++) {
      bf16x8 qf = kc ? qf1 : qf0;
#pragma unroll
      for (int kt = 0; kt < 4; kt++) {
        bf16x8 kf = *(const bf16x8*)&Kld[(kt * 16 + lr) * LP + kc * 32 + lg * 8];
        sacc[kt] = __builtin_amdgcn_mfma_f32_16x16x32_bf16(qf, kf, sacc[kt], 0, 0, 0);
      }
    }
#pragma unroll
    for (int kt = 0; kt < 4; kt++) sacc[kt] *= SC;
    // online softmax (exp2 domain), defer-rescale when max growth <= 8
    float pv[4][4];
#pragma unroll
    for (int r = 0; r < 4; r++) {
      float mx = fmaxf(fmaxf(sacc[0][r], sacc[1][r]), fmaxf(sacc[2][r], sacc[3][r]));
      mx = fmaxf(mx, __shfl_xor(mx, 1));
      mx = fmaxf(mx, __shfl_xor(mx, 2));
      mx = fmaxf(mx, __shfl_xor(mx, 4));
      mx = fmaxf(mx, __shfl_xor(mx, 8));
      if (__any(mx > mrun[r] + 8.0f)) {  // wave-uniform branch
        float mnew = fmaxf(mrun[r], mx);
        float corr = exp2f(mrun[r] - mnew);
        lrun[r] *= corr;
#pragma unroll
        for (int nt = 0; nt < 4; nt++) o[nt][r] *= corr;
        mrun[r] = mnew;
      }
      float ps = 0.0f;
#pragma unroll
      for (int kt = 0; kt < 4; kt++) {
        float p = exp2f(sacc[kt][r] - mrun[r]);  // bounded by 2^8
        pv[kt][r] = p; ps += p;
      }
      ps += __shfl_xor(ps, 1); ps += __shfl_xor(ps, 2);
      ps += __shfl_xor(ps, 4); ps += __shfl_xor(ps, 8);
      lrun[r] += ps;
    }
    // P -> per-wave LDS (layout shuffle to MFMA A-fragment)
#pragma unroll
    for (int kt = 0; kt < 4; kt++)
#pragma unroll
      for (int r = 0; r < 4; r++)
        Pld[wid][(lg * 4 + r) * LP + kt * 16 + lr] = (bf16_t)pv[kt][r];
    // O += P @ V
#pragma unroll
    for (int ks = 0; ks < 2; ks++) {
      bf16x8 pa = *(const bf16x8*)&Pld[wid][lr * LP + ks * 32 + lg * 8];
#pragma unroll
      for (int nt = 0; nt < 4; nt++) {
        bf16x8 vb = *(const bf16x8*)&Vld[(nt * 16 + lr) * LP + ks * 32 + lg * 8];
        o[nt] = __builtin_amdgcn_mfma_f32_16x16x32_bf16(pa, vb, o[nt], 0, 0, 0);
      }
    }
  }
#pragma unroll
  for (int nt = 0; nt < 4; nt++)
#pragma unroll
    for (int r = 0; r < 4; r++) {
      int qr = q0 + wid * 16 + lg * 4 + r;
      float val = o[nt][r] / lrun[r];
      ctx[((long)qr * B_ + bI) * (long)D_ + hI * 64 + nt * 16 + lr] = (bf16_t)val;
    }
}

// ------------- LN(base + bf16-add) -> fp32 out, one wave per row -------------
__global__ void k_ln_res(const float* __restrict__ base, const bf16_t* __restrict__ addb,
                         const float* __restrict__ g, const float* __restrict__ b,
                         float* __restrict__ out) {
  int w = (int)((blockIdx.x * blockDim.x + threadIdx.x) >> 6);
  int lane = threadIdx.x & 63;
  if (w >= NT) return;
  long off = (long)w * D_ + lane * 8;
  const float4* pb = (const float4*)(base + off);
  float4 b0 = pb[0], b1 = pb[1];
  bf16x8 av = *(const bf16x8*)(addb + off);
  float t[8];
  t[0]=b0.x+(float)av[0]; t[1]=b0.y+(float)av[1]; t[2]=b0.z+(float)av[2]; t[3]=b0.w+(float)av[3];
  t[4]=b1.x+(float)av[4]; t[5]=b1.y+(float)av[5]; t[6]=b1.z+(float)av[6]; t[7]=b1.w+(float)av[7];
  float s = t[0]+t[1]+t[2]+t[3]+t[4]+t[5]+t[6]+t[7];
  s = wave_sum(s);
  float mu = s * (1.0f / D_);
  float vv = 0.0f;
#pragma unroll
  for (int j = 0; j < 8; j++) { float d = t[j] - mu; vv += d * d; }
  vv = wave_sum(vv);
  float rstd = rsqrtf(vv * (1.0f / D_) + EPS_);
  const float4* pg = (const float4*)(g + lane * 8);
  const float4* pq = (const float4*)(b + lane * 8);
  float4 g0 = pg[0], g1 = pg[1], q0 = pq[0], q1 = pq[1];
  float4 o0, o1;
  o0.x=(t[0]-mu)*rstd*g0.x+q0.x; o0.y=(t[1]-mu)*rstd*g0.y+q0.y;
  o0.z=(t[2]-mu)*rstd*g0.z+q0.z; o0.w=(t[3]-mu)*rstd*g0.w+q0.w;
  o1.x=(t[4]-mu)*rstd*g1.x+q1.x; o1.y=(t[5]-mu)*rstd*g1.y+q1.y;
  o1.z=(t[6]-mu)*rstd*g1.z+q1.z; o1.w=(t[7]-mu)*rstd*g1.w+q1.w;
  float4* po = (float4*)(out + off);
  po[0] = o0; po[1] = o1;
}

// ------------- gate: softmax over 64 experts, one wave/token, lane=expert -------------
// 4 parallel accumulators: closer to BLAS blocked-sum order -> argmax-flip risk minimized.
__global__ void k_gate(const float* __restrict__ x, const float* __restrict__ gw,
                       int* __restrict__ eidx, float* __restrict__ gval) {
  int w = (int)((blockIdx.x * blockDim.x + threadIdx.x) >> 6);
  int lane = threadIdx.x & 63;
  if (w >= NT) return;
  const float* xr = x + (long)w * D_;
  float a0 = 0.0f, a1 = 0.0f, a2 = 0.0f, a3 = 0.0f;
#pragma unroll 4
  for (int k = 0; k < D_; k += 4) {
    a0 = fmaf(xr[k + 0], gw[(k + 0) * E_ + lane], a0);
    a1 = fmaf(xr[k + 1], gw[(k + 1) * E_ + lane], a1);
    a2 = fmaf(xr[k + 2], gw[(k + 2) * E_ + lane], a2);
    a3 = fmaf(xr[k + 3], gw[(k + 3) * E_ + lane], a3);
  }
  float acc = (a0 + a1) + (a2 + a3);
  float v = acc; int idx = lane;
#pragma unroll
  for (int m = 1; m < 64; m <<= 1) {
    float ov = __shfl_xor(v, m);
    int oi = __shfl_xor(idx, m);
    if (ov > v || (ov == v && oi < idx)) { v = ov; idx = oi; }
  }
  float s = __expf(acc - v);
  s = wave_sum(s);
  if (lane == 0) { eidx[w] = idx; gval[w] = 1.0f / s; }
}

// ------------- route: slot assign (atomic rank) + gather x row into xe (bf16) -------------
__global__ void k_route(const float* __restrict__ x, const int* __restrict__ eidx,
                        int* __restrict__ pos, int* __restrict__ cnt,
                        bf16_t* __restrict__ xe) {
  int w = (int)((blockIdx.x * blockDim.x + threadIdx.x) >> 6);
  int lane = threadIdx.x & 63;
  if (w >= NT) return;
  int e = eidx[w];
  int p = 0;
  if (lane == 0) p = atomicAdd(&cnt[e], 1);
  p = __shfl(p, 0);
  if (lane == 0) pos[w] = p;
  if (p < CAP) {
    const float4* px = (const float4*)(x + (long)w * D_ + lane * 8);
    float4 a = px[0], b = px[1];
    bf16x8 o;
    o[0]=(bf16_t)a.x; o[1]=(bf16_t)a.y; o[2]=(bf16_t)a.z; o[3]=(bf16_t)a.w;
    o[4]=(bf16_t)b.x; o[5]=(bf16_t)b.y; o[6]=(bf16_t)b.z; o[7]=(bf16_t)b.w;
    *(bf16x8*)(xe + ((long)e * CAP + p) * D_ + lane * 8) = o;
  }
}

// ------------- final: x + gval*ye[e][pos] -> LN2 -> d_out -------------
__global__ void k_final(const float* __restrict__ x, const bf16_t* __restrict__ ye,
                        const int* __restrict__ eidx, const int* __restrict__ pos,
                        const float* __restrict__ gval,
                        const float* __restrict__ g, const float* __restrict__ b,
                        float* __restrict__ out) {
  int w = (int)((blockIdx.x * blockDim.x + threadIdx.x) >> 6);
  int lane = threadIdx.x & 63;
  if (w >= NT) return;
  int e = eidx[w], p = pos[w];
  float gv = gval[w];
  long off = (long)w * D_ + lane * 8;
  const float4* px = (const float4*)(x + off);
  float4 x0 = px[0], x1 = px[1];
  float t[8] = {x0.x, x0.y, x0.z, x0.w, x1.x, x1.y, x1.z, x1.w};
  if (p < CAP) {
    bf16x8 yv = *(const bf16x8*)(ye + ((long)e * CAP + p) * D_ + lane * 8);
#pragma unroll
    for (int j = 0; j < 8; j++) t[j] += (float)yv[j] * gv;
  }
  float s = t[0]+t[1]+t[2]+t[3]+t[4]+t[5]+t[6]+t[7];
  s = wave_sum(s);
  float mu = s * (1.0f / D_);
  float vv = 0.0f;
#pragma unroll
  for (int j = 0; j < 8; j++) { float d = t[j] - mu; vv += d * d; }
  vv = wave_sum(vv);
  float rstd = rsqrtf(vv * (1.0f / D_) + EPS_);
  const float4* pg = (const float4*)(g + lane * 8);
  const float4* pq = (const float4*)(b + lane * 8);
  float4 g0 = pg[0], g1 = pg[1], q0 = pq[0], q1 = pq[1];
  float4 o0, o1;
  o0.x=(t[0]-mu)*rstd*g0.x+q0.x; o0.y=(t[1]-mu)*rstd*g0.y+q0.y;
  o0.z=(t[2]-mu)*rstd*g0.z+q0.z; o0.w=(t[3]-mu)*rstd*g0.w+q0.w;
  o1.x=(t[4]-mu)*rstd*g1.x+q1.x; o1.y=(t[5]-mu)*rstd*g1.y+q1.y;
  o1.z=(t[6]-mu)*rstd*g1.z+q1.z; o1.w=(t[7]-mu)*rstd*g1.w+q1.w;
  float4* po = (float4*)(out + off);
  po[0] = o0; po[1] = o1;
}

extern "C" void kernel_launch(void* const* d_in, const int* in_sizes, int n_in,
                              void* d_out, int out_size, void* d_ws, size_t ws_size,
                              hipStream_t stream) {
  const float* src        = (const float*)d_in[0];
  const float* in_proj_w  = (const float*)d_in[1];
  const float* in_proj_b  = (const float*)d_in[2];
  const float* out_proj_w = (const float*)d_in[3];
  const float* out_proj_b = (const float*)d_in[4];
  const float* ln1_g      = (const float*)d_in[5];
  const float* ln1_b      = (const float*)d_in[6];
  const float* gate_w     = (const float*)d_in[7];
  const float* w1         = (const float*)d_in[8];
  const float* b1         = (const float*)d_in[9];
  const float* w2         = (const float*)d_in[10];
  const float* b2         = (const float*)d_in[11];
  const float* ln2_g      = (const float*)d_in[12];
  const float* ln2_b      = (const float*)d_in[13];
  (void)in_sizes; (void)n_in; (void)out_size; (void)ws_size;

  // workspace layout (~600 MB total)
  char* ws = (char*)d_ws;
  size_t off = 0;
  auto alloc = [&](size_t bytes) -> char* {
    char* p = ws + off; off += (bytes + 255) & ~(size_t)255; return p;
  };
  bf16_t* src_bf  = (bf16_t*)alloc((size_t)NT * D_ * 2);
  bf16_t* w_in_bf = (bf16_t*)alloc((size_t)3 * D_ * D_ * 2);
  bf16_t* w_out_bf= (bf16_t*)alloc((size_t)D_ * D_ * 2);
  bf16_t* qkv_bf  = (bf16_t*)alloc((size_t)NT * 3 * D_ * 2);
  bf16_t* vT      = (bf16_t*)alloc((size_t)B_ * H_ * HD_ * S_ * 2);
  bf16_t* ctx_bf  = (bf16_t*)alloc((size_t)NT * D_ * 2);
  bf16_t* ao_bf   = (bf16_t*)alloc((size_t)NT * D_ * 2);
  float*  x_f32   = (float*)alloc((size_t)NT * D_ * 4);
  bf16_t* w1t     = (bf16_t*)alloc((size_t)E_ * D_ * F_ * 2);
  bf16_t* w2t     = (bf16_t*)alloc((size_t)E_ * F_ * D_ * 2);
  bf16_t* xe      = (bf16_t*)alloc((size_t)E_ * CAP * D_ * 2);
  bf16_t* hbuf    = (bf16_t*)alloc((size_t)E_ * CAP * F_ * 2);
  bf16_t* ye      = (bf16_t*)alloc((size_t)E_ * CAP * D_ * 2);
  int*    eidx    = (int*)alloc((size_t)NT * 4);
  int*    pos     = (int*)alloc((size_t)NT * 4);
  float*  gval    = (float*)alloc((size_t)NT * 4);
  int*    cnt     = (int*)alloc((size_t)E_ * 4);

  // 1) dtype conversions / weight transposes
  k_cvt<<<NT * D_ / 8 / 256, 256, 0, stream>>>(src, src_bf, NT * D_ / 8);
  k_cvt<<<3 * D_ * D_ / 8 / 256, 256, 0, stream>>>(in_proj_w, w_in_bf, 3 * D_ * D_ / 8);
  k_cvt<<<D_ * D_ / 8 / 256, 256, 0, stream>>>(out_proj_w, w_out_bf, D_ * D_ / 8);
  k_tcvt<<<dim3(F_ / 64, D_ / 64, E_), 256, 0, stream>>>(w1, w1t, D_, F_, (long)D_ * F_, (long)D_ * F_);
  k_tcvt<<<dim3(D_ / 64, F_ / 64, E_), 256, 0, stream>>>(w2, w2t, F_, D_, (long)F_ * D_, (long)F_ * D_);

  // 2) QKV projection
  k_gemm<0><<<dim3(12, 128, 1), 256, 0, stream>>>(src_bf, w_in_bf, in_proj_b, qkv_bf,
      512, 512, 512, 1536, 0, 0, 0, 0, nullptr, NT);

  // 3) attention
  k_tv<<<dim3(S_ / 64, B_ * H_), 256, 0, stream>>>(qkv_bf, vT);
  k_attn<<<dim3(S_ / 64, B_ * H_), 256, 0, stream>>>(qkv_bf, vT, ctx_bf);
  k_gemm<0><<<dim3(4, 128, 1), 256, 0, stream>>>(ctx_bf, w_out_bf, out_proj_b, ao_bf,
      512, 512, 512, 512, 0, 0, 0, 0, nullptr, NT);
  k_ln_res<<<NT / 4, 256, 0, stream>>>(src, ao_bf, ln1_g, ln1_b, x_f32);

  // 4) MoE routing
  k_gate<<<NT / 4, 256, 0, stream>>>(x_f32, gate_w, eidx, gval);
  hipMemsetAsync(cnt, 0, E_ * 4, stream);
  hipMemsetAsync(xe, 0, (size_t)E_ * CAP * D_ * 2, stream);
  k_route<<<NT / 4, 256, 0, stream>>>(x_f32, eidx, pos, cnt, xe);

  // 5) expert FFN (capacity-aware tile early-exit via cnt)
  k_gemm<1><<<dim3(F_ / 128, CAP / 128, E_), 256, 0, stream>>>(xe, w1t, b1, hbuf,
      512, 512, 512, 2048, (long)CAP * D_, (long)F_ * D_, (long)CAP * F_, F_, cnt, CAP);
  k_gemm<0><<<dim3(D_ / 128, CAP / 128, E_), 256, 0, stream>>>(hbuf, w2t, b2, ye,
      2048, 2048, 2048, 512, (long)CAP * F_, (long)F_ * D_, (long)CAP * D_, D_, cnt, CAP);

  // 6) scatter + residual + LN2 -> out
  k_final<<<NT / 4, 256, 0, stream>>>(x_f32, ye, eidx, pos, gval, ln2_g, ln2_b, (float*)d_out);
}

// Round 5
// 1338.323 us; speedup vs baseline: 1.0617x; 1.0617x over previous
//
#include <hip/hip_runtime.h>
#include <hip/hip_bf16.h>

typedef __bf16 bf16_t;
typedef __bf16 bf16x8 __attribute__((ext_vector_type(8)));
typedef float f32x4 __attribute__((ext_vector_type(4)));

static constexpr int S_ = 2048;
static constexpr int B_ = 8;
static constexpr int D_ = 512;
static constexpr int H_ = 8;
static constexpr int HD_ = 64;
static constexpr int F_ = 2048;
static constexpr int E_ = 64;
static constexpr int NT = S_ * B_;   // 16384 tokens
static constexpr int CAP = 512;      // expert capacity = 2*NT/E
static constexpr float EPS_ = 1e-5f;

__device__ __forceinline__ float wave_sum(float v) {
#pragma unroll
  for (int m = 1; m < 64; m <<= 1) v += __shfl_xor(v, m);
  return v;
}

// async global->LDS, 16B per lane; dest = wave-uniform base + lane*16 (m97/m104)
__device__ __forceinline__ void gload_lds16(const void* g, void* l) {
  __builtin_amdgcn_global_load_lds((const __attribute__((address_space(1))) void*)g,
                                   (__attribute__((address_space(3))) void*)l, 16, 0, 0);
}

__device__ __forceinline__ unsigned pack2bf(float lo, float hi) {
  union { bf16_t h; unsigned short u; } a, b;
  a.h = (bf16_t)lo; b.h = (bf16_t)hi;
  return ((unsigned)b.u << 16) | (unsigned)a.u;
}

// ---------------- f32 -> bf16 convert (vectorized 8/thread) ----------------
__global__ void k_cvt(const float* __restrict__ in, bf16_t* __restrict__ out, int n8) {
  int i = blockIdx.x * blockDim.x + threadIdx.x;
  if (i >= n8) return;
  const float4* p = (const float4*)in + (size_t)i * 2;
  float4 a = p[0], b = p[1];
  bf16x8 o;
  o[0]=(bf16_t)a.x; o[1]=(bf16_t)a.y; o[2]=(bf16_t)a.z; o[3]=(bf16_t)a.w;
  o[4]=(bf16_t)b.x; o[5]=(bf16_t)b.y; o[6]=(bf16_t)b.z; o[7]=(bf16_t)b.w;
  ((bf16x8*)out)[i] = o;
}

// ------- transpose+convert: per-expert [R][C] f32 -> [C][R] bf16 (64x64 tiles) -------
__global__ void k_tcvt(const float* __restrict__ in, bf16_t* __restrict__ out,
                       int R, int C, long strideIn, long strideOut) {
  __shared__ __align__(16) float t[64][68];
  const float* ip = in + (long)blockIdx.z * strideIn;
  bf16_t* op = out + (long)blockIdx.z * strideOut;
  int r0 = blockIdx.y * 64, c0 = blockIdx.x * 64;
  int tid = threadIdx.x;
  int row = tid >> 2, cc = (tid & 3) * 16;
  const float4* g = (const float4*)(ip + (long)(r0 + row) * C + c0 + cc);
  float4 a0 = g[0], a1 = g[1], a2 = g[2], a3 = g[3];
  *(float4*)&t[row][cc + 0]  = a0;
  *(float4*)&t[row][cc + 4]  = a1;
  *(float4*)&t[row][cc + 8]  = a2;
  *(float4*)&t[row][cc + 12] = a3;
  __syncthreads();
  int oc = tid >> 2, rr = (tid & 3) * 16;
  bf16x8 o0, o1;
#pragma unroll
  for (int j = 0; j < 8; j++) o0[j] = (bf16_t)t[rr + j][oc];
#pragma unroll
  for (int j = 0; j < 8; j++) o1[j] = (bf16_t)t[rr + 8 + j][oc];
  *(bf16x8*)(op + (long)(c0 + oc) * R + r0 + rr)     = o0;
  *(bf16x8*)(op + (long)(c0 + oc) * R + r0 + rr + 8) = o1;
}

// ---------- V transpose: vT[bh][d][s] = qkv[(s*B+b)*1536 + 1024 + h*64 + d] ----------
__global__ void k_tv(const bf16_t* __restrict__ qkv, bf16_t* __restrict__ vT) {
  __shared__ __align__(16) bf16_t t[64][72];
  int bh = blockIdx.y, bI = bh >> 3, hI = bh & 7;
  int s0 = blockIdx.x * 64;
  int tid = threadIdx.x;
  int row = tid >> 2, cc = (tid & 3) * 16;
  const uint4* g = (const uint4*)(qkv + ((long)(s0 + row) * B_ + bI) * 1536 + 1024 + hI * 64 + cc);
  uint4 v0 = g[0], v1 = g[1];
  *(uint4*)&t[row][cc]     = v0;
  *(uint4*)&t[row][cc + 8] = v1;
  __syncthreads();
  int oc = tid >> 2, rr = (tid & 3) * 16;
  bf16x8 o0, o1;
#pragma unroll
  for (int j = 0; j < 8; j++) o0[j] = t[rr + j][oc];
#pragma unroll
  for (int j = 0; j < 8; j++) o1[j] = t[rr + 8 + j][oc];
  bf16_t* op = vT + ((long)bh * 64 + oc) * (long)S_ + s0 + rr;
  *(bf16x8*)(op)     = o0;
  *(bf16x8*)(op + 8) = o1;
}

// ------------- NT bf16 GEMM: C[m][n] = sum_k A[m][k]*B[n][k] + bias[n] -------------
// m97 structure: 128x128 tile, BK=32, 4 waves, global_load_lds width-16 staging
// into LINEAR [128][32] LDS (dest must be lane-linear: rule #21), 2 barriers/K-step.
template <int RELU>
__global__ __launch_bounds__(256) void k_gemm(
    const bf16_t* __restrict__ A, const bf16_t* __restrict__ Bm,
    const float* __restrict__ bias, bf16_t* __restrict__ Cout,
    int K, int lda, int ldb, int ldc,
    long aStride, long bStride, long cStride, int biasStride,
    const int* __restrict__ cnt, int mCap) {
  __shared__ __align__(16) bf16_t As[128 * 32];
  __shared__ __align__(16) bf16_t Bs[128 * 32];
  int z = blockIdx.z;
  if (cnt) {
    int c = cnt[z]; if (c > mCap) c = mCap;
    if ((int)blockIdx.y * 128 >= c) return;
  }
  long m0 = (long)blockIdx.y * 128, n0 = (long)blockIdx.x * 128;
  const bf16_t* Ab = A + (long)z * aStride + m0 * lda;
  const bf16_t* Bb = Bm + (long)z * bStride + n0 * ldb;
  int tid = threadIdx.x, wid = tid >> 6, lane = tid & 63;
  int lr = lane & 15, lg = lane >> 4;
  int wm = wid >> 1, wn = wid & 1;
  // staging map: lane l of wave w -> row w*16 + l/4 (and +64), 16B chunk l%4
  int grow = wid * 16 + (lane >> 2);
  int gcol = (lane & 3) * 8;
  const bf16_t* gA0 = Ab + (long)grow * lda + gcol;
  const bf16_t* gA1 = gA0 + (long)64 * lda;
  const bf16_t* gB0 = Bb + (long)grow * ldb + gcol;
  const bf16_t* gB1 = gB0 + (long)64 * ldb;
  bf16_t* lA0 = &As[wid * 512 + lane * 8];
  bf16_t* lA1 = lA0 + 2048;
  bf16_t* lB0 = &Bs[wid * 512 + lane * 8];
  bf16_t* lB1 = lB0 + 2048;
  f32x4 acc[4][4] = {};
  for (int k0 = 0; k0 < K; k0 += 32) {
    gload_lds16(gA0 + k0, lA0);
    gload_lds16(gA1 + k0, lA1);
    gload_lds16(gB0 + k0, lB0);
    gload_lds16(gB1 + k0, lB1);
    __syncthreads();  // drains vmcnt (gload queue) + barrier
    bf16x8 af[4], bfr[4];
#pragma unroll
    for (int i = 0; i < 4; i++) {
      af[i]  = *(const bf16x8*)&As[(wm * 64 + i * 16 + lr) * 32 + lg * 8];
      bfr[i] = *(const bf16x8*)&Bs[(wn * 64 + i * 16 + lr) * 32 + lg * 8];
    }
#pragma unroll
    for (int i = 0; i < 4; i++)
#pragma unroll
      for (int j = 0; j < 4; j++)
        acc[i][j] = __builtin_amdgcn_mfma_f32_16x16x32_bf16(af[i], bfr[j], acc[i][j], 0, 0, 0);
    __syncthreads();  // all reads done before next stage overwrites
  }
  // epilogue: C layout col=lane&15, row=(lane>>4)*4+r (m89-verified)
#pragma unroll
  for (int j = 0; j < 4; j++) {
    int col = (int)n0 + wn * 64 + j * 16 + lr;
    float bv = bias[(long)z * biasStride + col];
#pragma unroll
    for (int i = 0; i < 4; i++) {
      long row = m0 + wm * 64 + i * 16 + lg * 4;
#pragma unroll
      for (int r = 0; r < 4; r++) {
        float v = acc[i][j][r] + bv;
        if (RELU) v = fmaxf(v, 0.0f);
        Cout[(long)z * cStride + (row + r) * ldc + col] = (bf16_t)v;
      }
    }
  }
}

// ---------------- flash attention fwd: one (64-row Q tile, b, h) per block ----------------
// Swapped QK^T (m214 structure): sacc = mfma(K,Q) -> lane holds S^T, so each lane's
// 16 S-values belong to ONE q-row (q=lane&15). Softmax row-reduce = in-register +
// 2 shfl_xor; P reaches PV A-frags via packed-u32 shfls. No P LDS buffer at all.
__global__ __launch_bounds__(256) void k_attn(const bf16_t* __restrict__ qkv,
                                              const bf16_t* __restrict__ vT,
                                              bf16_t* __restrict__ ctx) {
  constexpr int LP = 80;  // measured-best pitch for K/V b128 reads (R3)
  __shared__ __align__(16) bf16_t Kld[64 * LP];
  __shared__ __align__(16) bf16_t Vld[64 * LP];  // Vld[d][k]
  int bh = blockIdx.y, bI = bh >> 3, hI = bh & 7;
  int q0 = blockIdx.x * 64;
  int tid = threadIdx.x, wid = tid >> 6, lane = tid & 63;
  int lr = lane & 15, lg = lane >> 4;
  int qrow = q0 + wid * 16 + lr;
  const bf16_t* qb = qkv + ((long)qrow * B_ + bI) * 1536 + hI * 64;
  bf16x8 qf0 = *(const bf16x8*)(qb + lg * 8);
  bf16x8 qf1 = *(const bf16x8*)(qb + 32 + lg * 8);
  f32x4 o[4] = {};               // O[q=lg*4+r][d=nt*16+lr]
  float mrun = -3.0e38f, lrun = 0.0f;  // softmax state for q = lr (per-lane scalar)
  const float SC = 0.125f * 1.44269504f;  // 1/sqrt(64) * log2(e)
  int s0sh = lr + ((lane & 16) ? 32 : 0);  // P-shfl src: lr + 32*(lg&1)
  int hi = lg >> 1;
  int srow = tid >> 2, sc = (tid & 3) * 16;
  for (int kb = 0; kb < S_ / 64; kb++) {
    int krow = kb * 64 + srow;
    const uint4* kg = (const uint4*)(qkv + ((long)krow * B_ + bI) * 1536 + 512 + hI * 64 + sc);
    const uint4* vg = (const uint4*)(vT + ((long)bh * 64 + srow) * (long)S_ + kb * 64 + sc);
    uint4 k0v = kg[0], k1v = kg[1], v0v = vg[0], v1v = vg[1];
    __syncthreads();  // previous iteration's LDS reads done
    *(uint4*)&Kld[srow * LP + sc]     = k0v;
    *(uint4*)&Kld[srow * LP + sc + 8] = k1v;
    *(uint4*)&Vld[srow * LP + sc]     = v0v;
    *(uint4*)&Vld[srow * LP + sc + 8] = v1v;
    __syncthreads();
    // S^T = K Q^T: lane holds S[k=kt*16+lg*4+r][q=lr]
    f32x4 sacc[4] = {};
#pragma unroll
    for (int kc = 0; kc < 2; kc++) {
      bf16x8 qf = kc ? qf1 : qf0;
#pragma unroll
      for (int kt = 0; kt < 4; kt++) {
        bf16x8 kf = *(const bf16x8*)&Kld[(kt * 16 + lr) * LP + kc * 32 + lg * 8];
        sacc[kt] = __builtin_amdgcn_mfma_f32_16x16x32_bf16(kf, qf, sacc[kt], 0, 0, 0);
      }
    }
#pragma unroll
    for (int kt = 0; kt < 4; kt++) sacc[kt] *= SC;
    // row max for q=lr: 16 in-register + 2 shfl (combine lg groups)
    float mx = -3.0e38f;
#pragma unroll
    for (int kt = 0; kt < 4; kt++)
#pragma unroll
      for (int r = 0; r < 4; r++) mx = fmaxf(mx, sacc[kt][r]);
    mx = fmaxf(mx, __shfl_xor(mx, 16));
    mx = fmaxf(mx, __shfl_xor(mx, 32));
    float mnew = fmaxf(mrun, mx);
    float corr = exp2f(mrun - mnew);
    mrun = mnew;
    // P = exp2(S - m), packed to bf16x2 u32s; row sum
    float ps = 0.0f;
    unsigned pk[8];
#pragma unroll
    for (int kt = 0; kt < 4; kt++) {
      float p0 = exp2f(sacc[kt][0] - mnew);
      float p1 = exp2f(sacc[kt][1] - mnew);
      float p2 = exp2f(sacc[kt][2] - mnew);
      float p3 = exp2f(sacc[kt][3] - mnew);
      ps += (p0 + p1) + (p2 + p3);
      pk[kt * 2]     = pack2bf(p0, p1);
      pk[kt * 2 + 1] = pack2bf(p2, p3);
    }
    ps += __shfl_xor(ps, 16);
    ps += __shfl_xor(ps, 32);
    lrun = lrun * corr + ps;
    // rescale O: corr lives at q=lr layout; O rows are q=lg*4+r
    float cr[4];
#pragma unroll
    for (int r = 0; r < 4; r++) cr[r] = __shfl(corr, lg * 4 + r);
#pragma unroll
    for (int nt = 0; nt < 4; nt++)
#pragma unroll
      for (int r = 0; r < 4; r++) o[nt][r] *= cr[r];
    // redistribute P into A-frags: lane(lr,lg) needs k=[32ks+8lg,+8) of q-row lr,
    // owned by src lanes lr+32*(lg&1) (+16), kt = 2ks+(lg>>1). Two-round shfl + select.
#pragma unroll
    for (int ks = 0; ks < 2; ks++) {
      unsigned w[4];
#pragma unroll
      for (int h = 0; h < 2; h++) {
        unsigned vA = pk[4 * ks + h];       // kt = 2ks
        unsigned vB = pk[4 * ks + 2 + h];   // kt = 2ks+1
        unsigned a0 = (unsigned)__shfl((int)vA, s0sh);
        unsigned a1 = (unsigned)__shfl((int)vA, s0sh + 16);
        unsigned b0 = (unsigned)__shfl((int)vB, s0sh);
        unsigned b1 = (unsigned)__shfl((int)vB, s0sh + 16);
        w[h]     = hi ? b0 : a0;
        w[2 + h] = hi ? b1 : a1;
      }
      union { unsigned u[4]; bf16x8 v; } pw;
      pw.u[0] = w[0]; pw.u[1] = w[1]; pw.u[2] = w[2]; pw.u[3] = w[3];
#pragma unroll
      for (int nt = 0; nt < 4; nt++) {
        bf16x8 vb = *(const bf16x8*)&Vld[(nt * 16 + lr) * LP + ks * 32 + lg * 8];
        o[nt] = __builtin_amdgcn_mfma_f32_16x16x32_bf16(pw.v, vb, o[nt], 0, 0, 0);
      }
    }
  }
  float lr4[4];
#pragma unroll
  for (int r = 0; r < 4; r++) lr4[r] = __shfl(lrun, lg * 4 + r);
#pragma unroll
  for (int nt = 0; nt < 4; nt++)
#pragma unroll
    for (int r = 0; r < 4; r++) {
      int qr = q0 + wid * 16 + lg * 4 + r;
      float val = o[nt][r] / lr4[r];
      ctx[((long)qr * B_ + bI) * (long)D_ + hI * 64 + nt * 16 + lr] = (bf16_t)val;
    }
}

// ------------- LN(base + bf16-add) -> fp32 out, one wave per row -------------
__global__ void k_ln_res(const float* __restrict__ base, const bf16_t* __restrict__ addb,
                         const float* __restrict__ g, const float* __restrict__ b,
                         float* __restrict__ out) {
  int w = (int)((blockIdx.x * blockDim.x + threadIdx.x) >> 6);
  int lane = threadIdx.x & 63;
  if (w >= NT) return;
  long off = (long)w * D_ + lane * 8;
  const float4* pb = (const float4*)(base + off);
  float4 b0 = pb[0], b1 = pb[1];
  bf16x8 av = *(const bf16x8*)(addb + off);
  float t[8];
  t[0]=b0.x+(float)av[0]; t[1]=b0.y+(float)av[1]; t[2]=b0.z+(float)av[2]; t[3]=b0.w+(float)av[3];
  t[4]=b1.x+(float)av[4]; t[5]=b1.y+(float)av[5]; t[6]=b1.z+(float)av[6]; t[7]=b1.w+(float)av[7];
  float s = t[0]+t[1]+t[2]+t[3]+t[4]+t[5]+t[6]+t[7];
  s = wave_sum(s);
  float mu = s * (1.0f / D_);
  float vv = 0.0f;
#pragma unroll
  for (int j = 0; j < 8; j++) { float d = t[j] - mu; vv += d * d; }
  vv = wave_sum(vv);
  float rstd = rsqrtf(vv * (1.0f / D_) + EPS_);
  const float4* pg = (const float4*)(g + lane * 8);
  const float4* pq = (const float4*)(b + lane * 8);
  float4 g0 = pg[0], g1 = pg[1], q0 = pq[0], q1 = pq[1];
  float4 o0, o1;
  o0.x=(t[0]-mu)*rstd*g0.x+q0.x; o0.y=(t[1]-mu)*rstd*g0.y+q0.y;
  o0.z=(t[2]-mu)*rstd*g0.z+q0.z; o0.w=(t[3]-mu)*rstd*g0.w+q0.w;
  o1.x=(t[4]-mu)*rstd*g1.x+q1.x; o1.y=(t[5]-mu)*rstd*g1.y+q1.y;
  o1.z=(t[6]-mu)*rstd*g1.z+q1.z; o1.w=(t[7]-mu)*rstd*g1.w+q1.w;
  float4* po = (float4*)(out + off);
  po[0] = o0; po[1] = o1;
}

// ------------- gate: softmax over 64 experts, one wave/token, lane=expert -------------
// 4 parallel accumulators: closer to BLAS blocked-sum order -> argmax-flip risk minimized.
__global__ void k_gate(const float* __restrict__ x, const float* __restrict__ gw,
                       int* __restrict__ eidx, float* __restrict__ gval) {
  int w = (int)((blockIdx.x * blockDim.x + threadIdx.x) >> 6);
  int lane = threadIdx.x & 63;
  if (w >= NT) return;
  const float* xr = x + (long)w * D_;
  float a0 = 0.0f, a1 = 0.0f, a2 = 0.0f, a3 = 0.0f;
#pragma unroll 4
  for (int k = 0; k < D_; k += 4) {
    a0 = fmaf(xr[k + 0], gw[(k + 0) * E_ + lane], a0);
    a1 = fmaf(xr[k + 1], gw[(k + 1) * E_ + lane], a1);
    a2 = fmaf(xr[k + 2], gw[(k + 2) * E_ + lane], a2);
    a3 = fmaf(xr[k + 3], gw[(k + 3) * E_ + lane], a3);
  }
  float acc = (a0 + a1) + (a2 + a3);
  float v = acc; int idx = lane;
#pragma unroll
  for (int m = 1; m < 64; m <<= 1) {
    float ov = __shfl_xor(v, m);
    int oi = __shfl_xor(idx, m);
    if (ov > v || (ov == v && oi < idx)) { v = ov; idx = oi; }
  }
  float s = __expf(acc - v);
  s = wave_sum(s);
  if (lane == 0) { eidx[w] = idx; gval[w] = 1.0f / s; }
}

// ------------- route: slot assign (atomic rank) + gather x row into xe (bf16) -------------
__global__ void k_route(const float* __restrict__ x, const int* __restrict__ eidx,
                        int* __restrict__ pos, int* __restrict__ cnt,
                        bf16_t* __restrict__ xe) {
  int w = (int)((blockIdx.x * blockDim.x + threadIdx.x) >> 6);
  int lane = threadIdx.x & 63;
  if (w >= NT) return;
  int e = eidx[w];
  int p = 0;
  if (lane == 0) p = atomicAdd(&cnt[e], 1);
  p = __shfl(p, 0);
  if (lane == 0) pos[w] = p;
  if (p < CAP) {
    const float4* px = (const float4*)(x + (long)w * D_ + lane * 8);
    float4 a = px[0], b = px[1];
    bf16x8 o;
    o[0]=(bf16_t)a.x; o[1]=(bf16_t)a.y; o[2]=(bf16_t)a.z; o[3]=(bf16_t)a.w;
    o[4]=(bf16_t)b.x; o[5]=(bf16_t)b.y; o[6]=(bf16_t)b.z; o[7]=(bf16_t)b.w;
    *(bf16x8*)(xe + ((long)e * CAP + p) * D_ + lane * 8) = o;
  }
}

// ------------- final: x + gval*ye[e][pos] -> LN2 -> d_out -------------
__global__ void k_final(const float* __restrict__ x, const bf16_t* __restrict__ ye,
                        const int* __restrict__ eidx, const int* __restrict__ pos,
                        const float* __restrict__ gval,
                        const float* __restrict__ g, const float* __restrict__ b,
                        float* __restrict__ out) {
  int w = (int)((blockIdx.x * blockDim.x + threadIdx.x) >> 6);
  int lane = threadIdx.x & 63;
  if (w >= NT) return;
  int e = eidx[w], p = pos[w];
  float gv = gval[w];
  long off = (long)w * D_ + lane * 8;
  const float4* px = (const float4*)(x + off);
  float4 x0 = px[0], x1 = px[1];
  float t[8] = {x0.x, x0.y, x0.z, x0.w, x1.x, x1.y, x1.z, x1.w};
  if (p < CAP) {
    bf16x8 yv = *(const bf16x8*)(ye + ((long)e * CAP + p) * D_ + lane * 8);
#pragma unroll
    for (int j = 0; j < 8; j++) t[j] += (float)yv[j] * gv;
  }
  float s = t[0]+t[1]+t[2]+t[3]+t[4]+t[5]+t[6]+t[7];
  s = wave_sum(s);
  float mu = s * (1.0f / D_);
  float vv = 0.0f;
#pragma unroll
  for (int j = 0; j < 8; j++) { float d = t[j] - mu; vv += d * d; }
  vv = wave_sum(vv);
  float rstd = rsqrtf(vv * (1.0f / D_) + EPS_);
  const float4* pg = (const float4*)(g + lane * 8);
  const float4* pq = (const float4*)(b + lane * 8);
  float4 g0 = pg[0], g1 = pg[1], q0 = pq[0], q1 = pq[1];
  float4 o0, o1;
  o0.x=(t[0]-mu)*rstd*g0.x+q0.x; o0.y=(t[1]-mu)*rstd*g0.y+q0.y;
  o0.z=(t[2]-mu)*rstd*g0.z+q0.z; o0.w=(t[3]-mu)*rstd*g0.w+q0.w;
  o1.x=(t[4]-mu)*rstd*g1.x+q1.x; o1.y=(t[5]-mu)*rstd*g1.y+q1.y;
  o1.z=(t[6]-mu)*rstd*g1.z+q1.z; o1.w=(t[7]-mu)*rstd*g1.w+q1.w;
  float4* po = (float4*)(out + off);
  po[0] = o0; po[1] = o1;
}

extern "C" void kernel_launch(void* const* d_in, const int* in_sizes, int n_in,
                              void* d_out, int out_size, void* d_ws, size_t ws_size,
                              hipStream_t stream) {
  const float* src        = (const float*)d_in[0];
  const float* in_proj_w  = (const float*)d_in[1];
  const float* in_proj_b  = (const float*)d_in[2];
  const float* out_proj_w = (const float*)d_in[3];
  const float* out_proj_b = (const float*)d_in[4];
  const float* ln1_g      = (const float*)d_in[5];
  const float* ln1_b      = (const float*)d_in[6];
  const float* gate_w     = (const float*)d_in[7];
  const float* w1         = (const float*)d_in[8];
  const float* b1         = (const float*)d_in[9];
  const float* w2         = (const float*)d_in[10];
  const float* b2         = (const float*)d_in[11];
  const float* ln2_g      = (const float*)d_in[12];
  const float* ln2_b      = (const float*)d_in[13];
  (void)in_sizes; (void)n_in; (void)out_size; (void)ws_size;

  // workspace layout (~600 MB total)
  char* ws = (char*)d_ws;
  size_t off = 0;
  auto alloc = [&](size_t bytes) -> char* {
    char* p = ws + off; off += (bytes + 255) & ~(size_t)255; return p;
  };
  bf16_t* src_bf  = (bf16_t*)alloc((size_t)NT * D_ * 2);
  bf16_t* w_in_bf = (bf16_t*)alloc((size_t)3 * D_ * D_ * 2);
  bf16_t* w_out_bf= (bf16_t*)alloc((size_t)D_ * D_ * 2);
  bf16_t* qkv_bf  = (bf16_t*)alloc((size_t)NT * 3 * D_ * 2);
  bf16_t* vT      = (bf16_t*)alloc((size_t)B_ * H_ * HD_ * S_ * 2);
  bf16_t* ctx_bf  = (bf16_t*)alloc((size_t)NT * D_ * 2);
  bf16_t* ao_bf   = (bf16_t*)alloc((size_t)NT * D_ * 2);
  float*  x_f32   = (float*)alloc((size_t)NT * D_ * 4);
  bf16_t* w1t     = (bf16_t*)alloc((size_t)E_ * D_ * F_ * 2);
  bf16_t* w2t     = (bf16_t*)alloc((size_t)E_ * F_ * D_ * 2);
  bf16_t* xe      = (bf16_t*)alloc((size_t)E_ * CAP * D_ * 2);
  bf16_t* hbuf    = (bf16_t*)alloc((size_t)E_ * CAP * F_ * 2);
  bf16_t* ye      = (bf16_t*)alloc((size_t)E_ * CAP * D_ * 2);
  int*    eidx    = (int*)alloc((size_t)NT * 4);
  int*    pos     = (int*)alloc((size_t)NT * 4);
  float*  gval    = (float*)alloc((size_t)NT * 4);
  int*    cnt     = (int*)alloc((size_t)E_ * 4);

  // 1) dtype conversions / weight transposes
  k_cvt<<<NT * D_ / 8 / 256, 256, 0, stream>>>(src, src_bf, NT * D_ / 8);
  k_cvt<<<3 * D_ * D_ / 8 / 256, 256, 0, stream>>>(in_proj_w, w_in_bf, 3 * D_ * D_ / 8);
  k_cvt<<<D_ * D_ / 8 / 256, 256, 0, stream>>>(out_proj_w, w_out_bf, D_ * D_ / 8);
  k_tcvt<<<dim3(F_ / 64, D_ / 64, E_), 256, 0, stream>>>(w1, w1t, D_, F_, (long)D_ * F_, (long)D_ * F_);
  k_tcvt<<<dim3(D_ / 64, F_ / 64, E_), 256, 0, stream>>>(w2, w2t, F_, D_, (long)F_ * D_, (long)F_ * D_);

  // 2) QKV projection
  k_gemm<0><<<dim3(12, 128, 1), 256, 0, stream>>>(src_bf, w_in_bf, in_proj_b, qkv_bf,
      512, 512, 512, 1536, 0, 0, 0, 0, nullptr, NT);

  // 3) attention
  k_tv<<<dim3(S_ / 64, B_ * H_), 256, 0, stream>>>(qkv_bf, vT);
  k_attn<<<dim3(S_ / 64, B_ * H_), 256, 0, stream>>>(qkv_bf, vT, ctx_bf);
  k_gemm<0><<<dim3(4, 128, 1), 256, 0, stream>>>(ctx_bf, w_out_bf, out_proj_b, ao_bf,
      512, 512, 512, 512, 0, 0, 0, 0, nullptr, NT);
  k_ln_res<<<NT / 4, 256, 0, stream>>>(src, ao_bf, ln1_g, ln1_b, x_f32);

  // 4) MoE routing
  k_gate<<<NT / 4, 256, 0, stream>>>(x_f32, gate_w, eidx, gval);
  hipMemsetAsync(cnt, 0, E_ * 4, stream);
  hipMemsetAsync(xe, 0, (size_t)E_ * CAP * D_ * 2, stream);
  k_route<<<NT / 4, 256, 0, stream>>>(x_f32, eidx, pos, cnt, xe);

  // 5) expert FFN (capacity-aware tile early-exit via cnt)
  k_gemm<1><<<dim3(F_ / 128, CAP / 128, E_), 256, 0, stream>>>(xe, w1t, b1, hbuf,
      512, 512, 512, 2048, (long)CAP * D_, (long)F_ * D_, (long)CAP * F_, F_, cnt, CAP);
  k_gemm<0><<<dim3(D_ / 128, CAP / 128, E_), 256, 0, stream>>>(hbuf, w2t, b2, ye,
      2048, 2048, 2048, 512, (long)CAP * F_, (long)F_ * D_, (long)CAP * D_, D_, cnt, CAP);

  // 6) scatter + residual + LN2 -> out
  k_final<<<NT / 4, 256, 0, stream>>>(x_f32, ye, eidx, pos, gval, ln2_g, ln2_b, (float*)d_out);
}

// Round 6
// 1298.055 us; speedup vs baseline: 1.0946x; 1.0310x over previous
//
#include <hip/hip_runtime.h>
#include <hip/hip_bf16.h>

typedef __bf16 bf16_t;
typedef __bf16 bf16x8 __attribute__((ext_vector_type(8)));
typedef float f32x4 __attribute__((ext_vector_type(4)));

static constexpr int S_ = 2048;
static constexpr int B_ = 8;
static constexpr int D_ = 512;
static constexpr int H_ = 8;
static constexpr int HD_ = 64;
static constexpr int F_ = 2048;
static constexpr int E_ = 64;
static constexpr int NT = S_ * B_;   // 16384 tokens
static constexpr int CAP = 512;      // expert capacity = 2*NT/E
static constexpr float EPS_ = 1e-5f;

__device__ __forceinline__ float wave_sum(float v) {
#pragma unroll
  for (int m = 1; m < 64; m <<= 1) v += __shfl_xor(v, m);
  return v;
}

// async global->LDS, 16B per lane; dest = wave-uniform base + lane*16 (m97/m104)
__device__ __forceinline__ void gload_lds16(const void* g, void* l) {
  __builtin_amdgcn_global_load_lds((const __attribute__((address_space(1))) void*)g,
                                   (__attribute__((address_space(3))) void*)l, 16, 0, 0);
}

__device__ __forceinline__ unsigned pack2bf(float lo, float hi) {
  union { bf16_t h; unsigned short u; } a, b;
  a.h = (bf16_t)lo; b.h = (bf16_t)hi;
  return ((unsigned)b.u << 16) | (unsigned)a.u;
}

// ---------------- f32 -> bf16 convert (vectorized 8/thread) ----------------
__global__ void k_cvt(const float* __restrict__ in, bf16_t* __restrict__ out, int n8) {
  int i = blockIdx.x * blockDim.x + threadIdx.x;
  if (i >= n8) return;
  const float4* p = (const float4*)in + (size_t)i * 2;
  float4 a = p[0], b = p[1];
  bf16x8 o;
  o[0]=(bf16_t)a.x; o[1]=(bf16_t)a.y; o[2]=(bf16_t)a.z; o[3]=(bf16_t)a.w;
  o[4]=(bf16_t)b.x; o[5]=(bf16_t)b.y; o[6]=(bf16_t)b.z; o[7]=(bf16_t)b.w;
  ((bf16x8*)out)[i] = o;
}

// ------- transpose+convert: per-z [R][C] f32 -> [C][R] bf16, 64x64 tiles -------
// Coalesced: load = 16 lanes x 16B per row (256B/row-instr); store = 8 lanes x 16B
// per out-row (128B). LDS pad 65 -> 2-way b32 reads (free, m136).
__global__ void k_tcvt(const float* __restrict__ in, bf16_t* __restrict__ out,
                       int R, int C, long strideIn, long strideOut) {
  __shared__ float t[64][65];
  const float* ip = in + (long)blockIdx.z * strideIn;
  bf16_t* op = out + (long)blockIdx.z * strideOut;
  int r0 = blockIdx.y * 64, c0 = blockIdx.x * 64;
  int tid = threadIdx.x;
  int lrow = tid >> 4, lch = tid & 15;
#pragma unroll
  for (int i = 0; i < 4; i++) {
    int row = lrow + i * 16;
    float4 v = *(const float4*)(ip + (long)(r0 + row) * C + c0 + lch * 4);
    *(float4*)&t[row][lch * 4] = v;
  }
  __syncthreads();
  int scrow = tid >> 3, sch = tid & 7;
#pragma unroll
  for (int i = 0; i < 2; i++) {
    int c = scrow + i * 32;
    bf16x8 o;
#pragma unroll
    for (int j = 0; j < 8; j++) o[j] = (bf16_t)t[sch * 8 + j][c];
    *(bf16x8*)(op + (long)(c0 + c) * R + r0 + sch * 8) = o;
  }
}

// ---------- V transpose: vT[bh][d][s] = qkv[(s*B+b)*1536 + 1024 + h*64 + d] ----------
__global__ void k_tv(const bf16_t* __restrict__ qkv, bf16_t* __restrict__ vT) {
  __shared__ __align__(16) bf16_t t[64][72];
  int bh = blockIdx.y, bI = bh >> 3, hI = bh & 7;
  int s0 = blockIdx.x * 64;
  int tid = threadIdx.x;
  int row = tid >> 2, cc = (tid & 3) * 16;
  const uint4* g = (const uint4*)(qkv + ((long)(s0 + row) * B_ + bI) * 1536 + 1024 + hI * 64 + cc);
  uint4 v0 = g[0], v1 = g[1];
  *(uint4*)&t[row][cc]     = v0;
  *(uint4*)&t[row][cc + 8] = v1;
  __syncthreads();
  int oc = tid >> 2, rr = (tid & 3) * 16;
  bf16x8 o0, o1;
#pragma unroll
  for (int j = 0; j < 8; j++) o0[j] = t[rr + j][oc];
#pragma unroll
  for (int j = 0; j < 8; j++) o1[j] = t[rr + 8 + j][oc];
  bf16_t* op = vT + ((long)bh * 64 + oc) * (long)S_ + s0 + rr;
  *(bf16x8*)(op)     = o0;
  *(bf16x8*)(op + 8) = o1;
}

// ------------- NT bf16 GEMM: C[m][n] = sum_k A[m][k]*B[n][k] + bias[n] -------------
// m97 structure: 128x128 tile, BK=32, 4 waves, global_load_lds width-16 staging
// into LINEAR [128][32] LDS (dest must be lane-linear: rule #21), 2 barriers/K-step.
template <int RELU>
__global__ __launch_bounds__(256) void k_gemm(
    const bf16_t* __restrict__ A, const bf16_t* __restrict__ Bm,
    const float* __restrict__ bias, bf16_t* __restrict__ Cout,
    int K, int lda, int ldb, int ldc,
    long aStride, long bStride, long cStride, int biasStride,
    const int* __restrict__ cnt, int mCap) {
  __shared__ __align__(16) bf16_t As[128 * 32];
  __shared__ __align__(16) bf16_t Bs[128 * 32];
  int z = blockIdx.z;
  if (cnt) {
    int c = cnt[z]; if (c > mCap) c = mCap;
    if ((int)blockIdx.y * 128 >= c) return;
  }
  long m0 = (long)blockIdx.y * 128, n0 = (long)blockIdx.x * 128;
  const bf16_t* Ab = A + (long)z * aStride + m0 * lda;
  const bf16_t* Bb = Bm + (long)z * bStride + n0 * ldb;
  int tid = threadIdx.x, wid = tid >> 6, lane = tid & 63;
  int lr = lane & 15, lg = lane >> 4;
  int wm = wid >> 1, wn = wid & 1;
  // staging map: lane l of wave w -> row w*16 + l/4 (and +64), 16B chunk l%4
  int grow = wid * 16 + (lane >> 2);
  int gcol = (lane & 3) * 8;
  const bf16_t* gA0 = Ab + (long)grow * lda + gcol;
  const bf16_t* gA1 = gA0 + (long)64 * lda;
  const bf16_t* gB0 = Bb + (long)grow * ldb + gcol;
  const bf16_t* gB1 = gB0 + (long)64 * ldb;
  bf16_t* lA0 = &As[wid * 512 + lane * 8];
  bf16_t* lA1 = lA0 + 2048;
  bf16_t* lB0 = &Bs[wid * 512 + lane * 8];
  bf16_t* lB1 = lB0 + 2048;
  f32x4 acc[4][4] = {};
  for (int k0 = 0; k0 < K; k0 += 32) {
    gload_lds16(gA0 + k0, lA0);
    gload_lds16(gA1 + k0, lA1);
    gload_lds16(gB0 + k0, lB0);
    gload_lds16(gB1 + k0, lB1);
    __syncthreads();  // drains vmcnt (gload queue) + barrier
    bf16x8 af[4], bfr[4];
#pragma unroll
    for (int i = 0; i < 4; i++) {
      af[i]  = *(const bf16x8*)&As[(wm * 64 + i * 16 + lr) * 32 + lg * 8];
      bfr[i] = *(const bf16x8*)&Bs[(wn * 64 + i * 16 + lr) * 32 + lg * 8];
    }
#pragma unroll
    for (int i = 0; i < 4; i++)
#pragma unroll
      for (int j = 0; j < 4; j++)
        acc[i][j] = __builtin_amdgcn_mfma_f32_16x16x32_bf16(af[i], bfr[j], acc[i][j], 0, 0, 0);
    __syncthreads();  // all reads done before next stage overwrites
  }
  // epilogue: C layout col=lane&15, row=(lane>>4)*4+r (m89-verified)
#pragma unroll
  for (int j = 0; j < 4; j++) {
    int col = (int)n0 + wn * 64 + j * 16 + lr;
    float bv = bias[(long)z * biasStride + col];
#pragma unroll
    for (int i = 0; i < 4; i++) {
      long row = m0 + wm * 64 + i * 16 + lg * 4;
#pragma unroll
      for (int r = 0; r < 4; r++) {
        float v = acc[i][j][r] + bv;
        if (RELU) v = fmaxf(v, 0.0f);
        Cout[(long)z * cStride + (row + r) * ldc + col] = (bf16_t)v;
      }
    }
  }
}

// ---------------- flash attention fwd: one (64-row Q tile, b, h) per block ----------------
// Swapped QK^T (m214): lane holds S^T, q=lane&15 -> in-register softmax, P via shfl.
// Defer-rescale THR=8 (T13): skip corr shfls + O-rescale when max growth <= 8 (exp2 dom).
__global__ __launch_bounds__(256) void k_attn(const bf16_t* __restrict__ qkv,
                                              const bf16_t* __restrict__ vT,
                                              bf16_t* __restrict__ ctx) {
  constexpr int LP = 80;  // measured-best pitch for K/V b128 reads (R3/R5)
  __shared__ __align__(16) bf16_t Kld[64 * LP];
  __shared__ __align__(16) bf16_t Vld[64 * LP];  // Vld[d][k]
  int bh = blockIdx.y, bI = bh >> 3, hI = bh & 7;
  int q0 = blockIdx.x * 64;
  int tid = threadIdx.x, wid = tid >> 6, lane = tid & 63;
  int lr = lane & 15, lg = lane >> 4;
  int qrow = q0 + wid * 16 + lr;
  const bf16_t* qb = qkv + ((long)qrow * B_ + bI) * 1536 + hI * 64;
  bf16x8 qf0 = *(const bf16x8*)(qb + lg * 8);
  bf16x8 qf1 = *(const bf16x8*)(qb + 32 + lg * 8);
  f32x4 o[4] = {};               // O[q=lg*4+r][d=nt*16+lr]
  float mrun = -3.0e38f, lrun = 0.0f;  // softmax state for q = lr (per-lane scalar)
  const float SC = 0.125f * 1.44269504f;  // 1/sqrt(64) * log2(e)
  int s0sh = lr + ((lane & 16) ? 32 : 0);  // P-shfl src: lr + 32*(lg&1)
  int hi = lg >> 1;
  int srow = tid >> 2, sc = (tid & 3) * 16;
  for (int kb = 0; kb < S_ / 64; kb++) {
    int krow = kb * 64 + srow;
    const uint4* kg = (const uint4*)(qkv + ((long)krow * B_ + bI) * 1536 + 512 + hI * 64 + sc);
    const uint4* vg = (const uint4*)(vT + ((long)bh * 64 + srow) * (long)S_ + kb * 64 + sc);
    uint4 k0v = kg[0], k1v = kg[1], v0v = vg[0], v1v = vg[1];
    __syncthreads();  // previous iteration's LDS reads done
    *(uint4*)&Kld[srow * LP + sc]     = k0v;
    *(uint4*)&Kld[srow * LP + sc + 8] = k1v;
    *(uint4*)&Vld[srow * LP + sc]     = v0v;
    *(uint4*)&Vld[srow * LP + sc + 8] = v1v;
    __syncthreads();
    // S^T = K Q^T: lane holds S[k=kt*16+lg*4+r][q=lr]
    f32x4 sacc[4] = {};
#pragma unroll
    for (int kc = 0; kc < 2; kc++) {
      bf16x8 qf = kc ? qf1 : qf0;
#pragma unroll
      for (int kt = 0; kt < 4; kt++) {
        bf16x8 kf = *(const bf16x8*)&Kld[(kt * 16 + lr) * LP + kc * 32 + lg * 8];
        sacc[kt] = __builtin_amdgcn_mfma_f32_16x16x32_bf16(kf, qf, sacc[kt], 0, 0, 0);
      }
    }
#pragma unroll
    for (int kt = 0; kt < 4; kt++) sacc[kt] *= SC;
    // row max for q=lr: 16 in-register + 2 shfl (combine lg groups)
    float mx = -3.0e38f;
#pragma unroll
    for (int kt = 0; kt < 4; kt++)
#pragma unroll
      for (int r = 0; r < 4; r++) mx = fmaxf(mx, sacc[kt][r]);
    mx = fmaxf(mx, __shfl_xor(mx, 16));
    mx = fmaxf(mx, __shfl_xor(mx, 32));
    if (__any(mx > mrun + 8.0f)) {  // defer-rescale: run only on real growth
      float mnew = fmaxf(mrun, mx);
      float corr = exp2f(mrun - mnew);
      mrun = mnew;
      lrun *= corr;
      float cr[4];
#pragma unroll
      for (int r = 0; r < 4; r++) cr[r] = __shfl(corr, lg * 4 + r);
#pragma unroll
      for (int nt = 0; nt < 4; nt++)
#pragma unroll
        for (int r = 0; r < 4; r++) o[nt][r] *= cr[r];
    }
    // P = exp2(S - mrun) (bounded by 2^8), packed to bf16x2 u32s; row sum
    float ps = 0.0f;
    unsigned pk[8];
#pragma unroll
    for (int kt = 0; kt < 4; kt++) {
      float p0 = exp2f(sacc[kt][0] - mrun);
      float p1 = exp2f(sacc[kt][1] - mrun);
      float p2 = exp2f(sacc[kt][2] - mrun);
      float p3 = exp2f(sacc[kt][3] - mrun);
      ps += (p0 + p1) + (p2 + p3);
      pk[kt * 2]     = pack2bf(p0, p1);
      pk[kt * 2 + 1] = pack2bf(p2, p3);
    }
    ps += __shfl_xor(ps, 16);
    ps += __shfl_xor(ps, 32);
    lrun += ps;
    // redistribute P into A-frags: lane(lr,lg) needs k=[32ks+8lg,+8) of q-row lr,
    // owned by src lanes lr+32*(lg&1) (+16), kt = 2ks+(lg>>1). Two-round shfl + select.
#pragma unroll
    for (int ks = 0; ks < 2; ks++) {
      unsigned w[4];
#pragma unroll
      for (int h = 0; h < 2; h++) {
        unsigned vA = pk[4 * ks + h];       // kt = 2ks
        unsigned vB = pk[4 * ks + 2 + h];   // kt = 2ks+1
        unsigned a0 = (unsigned)__shfl((int)vA, s0sh);
        unsigned a1 = (unsigned)__shfl((int)vA, s0sh + 16);
        unsigned b0 = (unsigned)__shfl((int)vB, s0sh);
        unsigned b1 = (unsigned)__shfl((int)vB, s0sh + 16);
        w[h]     = hi ? b0 : a0;
        w[2 + h] = hi ? b1 : a1;
      }
      union { unsigned u[4]; bf16x8 v; } pw;
      pw.u[0] = w[0]; pw.u[1] = w[1]; pw.u[2] = w[2]; pw.u[3] = w[3];
#pragma unroll
      for (int nt = 0; nt < 4; nt++) {
        bf16x8 vb = *(const bf16x8*)&Vld[(nt * 16 + lr) * LP + ks * 32 + lg * 8];
        o[nt] = __builtin_amdgcn_mfma_f32_16x16x32_bf16(pw.v, vb, o[nt], 0, 0, 0);
      }
    }
  }
  float lr4[4];
#pragma unroll
  for (int r = 0; r < 4; r++) lr4[r] = __shfl(lrun, lg * 4 + r);
#pragma unroll
  for (int nt = 0; nt < 4; nt++)
#pragma unroll
    for (int r = 0; r < 4; r++) {
      int qr = q0 + wid * 16 + lg * 4 + r;
      float val = o[nt][r] / lr4[r];
      ctx[((long)qr * B_ + bI) * (long)D_ + hI * 64 + nt * 16 + lr] = (bf16_t)val;
    }
}

// ------------- LN(base + bf16-add) -> fp32 out + bf16 copy, one wave per row -------------
__global__ void k_ln_res(const float* __restrict__ base, const bf16_t* __restrict__ addb,
                         const float* __restrict__ g, const float* __restrict__ b,
                         float* __restrict__ out, bf16_t* __restrict__ outb) {
  int w = (int)((blockIdx.x * blockDim.x + threadIdx.x) >> 6);
  int lane = threadIdx.x & 63;
  if (w >= NT) return;
  long off = (long)w * D_ + lane * 8;
  const float4* pb = (const float4*)(base + off);
  float4 b0 = pb[0], b1 = pb[1];
  bf16x8 av = *(const bf16x8*)(addb + off);
  float t[8];
  t[0]=b0.x+(float)av[0]; t[1]=b0.y+(float)av[1]; t[2]=b0.z+(float)av[2]; t[3]=b0.w+(float)av[3];
  t[4]=b1.x+(float)av[4]; t[5]=b1.y+(float)av[5]; t[6]=b1.z+(float)av[6]; t[7]=b1.w+(float)av[7];
  float s = t[0]+t[1]+t[2]+t[3]+t[4]+t[5]+t[6]+t[7];
  s = wave_sum(s);
  float mu = s * (1.0f / D_);
  float vv = 0.0f;
#pragma unroll
  for (int j = 0; j < 8; j++) { float d = t[j] - mu; vv += d * d; }
  vv = wave_sum(vv);
  float rstd = rsqrtf(vv * (1.0f / D_) + EPS_);
  const float4* pg = (const float4*)(g + lane * 8);
  const float4* pq = (const float4*)(b + lane * 8);
  float4 g0 = pg[0], g1 = pg[1], q0 = pq[0], q1 = pq[1];
  float4 o0, o1;
  o0.x=(t[0]-mu)*rstd*g0.x+q0.x; o0.y=(t[1]-mu)*rstd*g0.y+q0.y;
  o0.z=(t[2]-mu)*rstd*g0.z+q0.z; o0.w=(t[3]-mu)*rstd*g0.w+q0.w;
  o1.x=(t[4]-mu)*rstd*g1.x+q1.x; o1.y=(t[5]-mu)*rstd*g1.y+q1.y;
  o1.z=(t[6]-mu)*rstd*g1.z+q1.z; o1.w=(t[7]-mu)*rstd*g1.w+q1.w;
  float4* po = (float4*)(out + off);
  po[0] = o0; po[1] = o1;
  bf16x8 xb;
  xb[0]=(bf16_t)o0.x; xb[1]=(bf16_t)o0.y; xb[2]=(bf16_t)o0.z; xb[3]=(bf16_t)o0.w;
  xb[4]=(bf16_t)o1.x; xb[5]=(bf16_t)o1.y; xb[6]=(bf16_t)o1.z; xb[7]=(bf16_t)o1.w;
  *(bf16x8*)(outb + off) = xb;
}

// ------------- gate: 4 tokens/wave (4x gw reuse), lane=expert -------------
// Per-token 4-accumulator order identical to R5 (argmax parity preserved).
__global__ void k_gate(const float* __restrict__ x, const float* __restrict__ gw,
                       int* __restrict__ eidx, float* __restrict__ gval) {
  int w = (int)((blockIdx.x * blockDim.x + threadIdx.x) >> 6);
  int lane = threadIdx.x & 63;
  if (w >= NT / 4) return;
  const float* xr = x + (long)w * 4 * D_;
  float a[4][4] = {};
  for (int k = 0; k < D_; k += 4) {
    float g0 = gw[(k + 0) * E_ + lane];
    float g1 = gw[(k + 1) * E_ + lane];
    float g2 = gw[(k + 2) * E_ + lane];
    float g3 = gw[(k + 3) * E_ + lane];
#pragma unroll
    for (int tk = 0; tk < 4; tk++) {
      const float* xt = xr + tk * D_;
      a[tk][0] = fmaf(xt[k + 0], g0, a[tk][0]);
      a[tk][1] = fmaf(xt[k + 1], g1, a[tk][1]);
      a[tk][2] = fmaf(xt[k + 2], g2, a[tk][2]);
      a[tk][3] = fmaf(xt[k + 3], g3, a[tk][3]);
    }
  }
#pragma unroll
  for (int tk = 0; tk < 4; tk++) {
    float acc = (a[tk][0] + a[tk][1]) + (a[tk][2] + a[tk][3]);
    float v = acc; int idx = lane;
#pragma unroll
    for (int m = 1; m < 64; m <<= 1) {
      float ov = __shfl_xor(v, m);
      int oi = __shfl_xor(idx, m);
      if (ov > v || (ov == v && oi < idx)) { v = ov; idx = oi; }
    }
    float s = wave_sum(__expf(acc - v));
    if (lane == 0) { eidx[w * 4 + tk] = idx; gval[w * 4 + tk] = 1.0f / s; }
  }
}

// ------------- route: slot assign (atomic rank) + gather x_bf row into xe -------------
__global__ void k_route(const bf16_t* __restrict__ xbf, const int* __restrict__ eidx,
                        int* __restrict__ pos, int* __restrict__ cnt,
                        bf16_t* __restrict__ xe) {
  int w = (int)((blockIdx.x * blockDim.x + threadIdx.x) >> 6);
  int lane = threadIdx.x & 63;
  if (w >= NT) return;
  int e = eidx[w];
  int p = 0;
  if (lane == 0) p = atomicAdd(&cnt[e], 1);
  p = __shfl(p, 0);
  if (lane == 0) pos[w] = p;
  if (p < CAP) {
    bf16x8 o = *(const bf16x8*)(xbf + (long)w * D_ + lane * 8);
    *(bf16x8*)(xe + ((long)e * CAP + p) * D_ + lane * 8) = o;
  }
}

// ------------- final: x + gval*ye[e][pos] -> LN2 -> d_out -------------
__global__ void k_final(const float* __restrict__ x, const bf16_t* __restrict__ ye,
                        const int* __restrict__ eidx, const int* __restrict__ pos,
                        const float* __restrict__ gval,
                        const float* __restrict__ g, const float* __restrict__ b,
                        float* __restrict__ out) {
  int w = (int)((blockIdx.x * blockDim.x + threadIdx.x) >> 6);
  int lane = threadIdx.x & 63;
  if (w >= NT) return;
  int e = eidx[w], p = pos[w];
  float gv = gval[w];
  long off = (long)w * D_ + lane * 8;
  const float4* px = (const float4*)(x + off);
  float4 x0 = px[0], x1 = px[1];
  float t[8] = {x0.x, x0.y, x0.z, x0.w, x1.x, x1.y, x1.z, x1.w};
  if (p < CAP) {
    bf16x8 yv = *(const bf16x8*)(ye + ((long)e * CAP + p) * D_ + lane * 8);
#pragma unroll
    for (int j = 0; j < 8; j++) t[j] += (float)yv[j] * gv;
  }
  float s = t[0]+t[1]+t[2]+t[3]+t[4]+t[5]+t[6]+t[7];
  s = wave_sum(s);
  float mu = s * (1.0f / D_);
  float vv = 0.0f;
#pragma unroll
  for (int j = 0; j < 8; j++) { float d = t[j] - mu; vv += d * d; }
  vv = wave_sum(vv);
  float rstd = rsqrtf(vv * (1.0f / D_) + EPS_);
  const float4* pg = (const float4*)(g + lane * 8);
  const float4* pq = (const float4*)(b + lane * 8);
  float4 g0 = pg[0], g1 = pg[1], q0 = pq[0], q1 = pq[1];
  float4 o0, o1;
  o0.x=(t[0]-mu)*rstd*g0.x+q0.x; o0.y=(t[1]-mu)*rstd*g0.y+q0.y;
  o0.z=(t[2]-mu)*rstd*g0.z+q0.z; o0.w=(t[3]-mu)*rstd*g0.w+q0.w;
  o1.x=(t[4]-mu)*rstd*g1.x+q1.x; o1.y=(t[5]-mu)*rstd*g1.y+q1.y;
  o1.z=(t[6]-mu)*rstd*g1.z+q1.z; o1.w=(t[7]-mu)*rstd*g1.w+q1.w;
  float4* po = (float4*)(out + off);
  po[0] = o0; po[1] = o1;
}

extern "C" void kernel_launch(void* const* d_in, const int* in_sizes, int n_in,
                              void* d_out, int out_size, void* d_ws, size_t ws_size,
                              hipStream_t stream) {
  const float* src        = (const float*)d_in[0];
  const float* in_proj_w  = (const float*)d_in[1];
  const float* in_proj_b  = (const float*)d_in[2];
  const float* out_proj_w = (const float*)d_in[3];
  const float* out_proj_b = (const float*)d_in[4];
  const float* ln1_g      = (const float*)d_in[5];
  const float* ln1_b      = (const float*)d_in[6];
  const float* gate_w     = (const float*)d_in[7];
  const float* w1         = (const float*)d_in[8];
  const float* b1         = (const float*)d_in[9];
  const float* w2         = (const float*)d_in[10];
  const float* b2         = (const float*)d_in[11];
  const float* ln2_g      = (const float*)d_in[12];
  const float* ln2_b      = (const float*)d_in[13];
  (void)in_sizes; (void)n_in; (void)out_size; (void)ws_size;

  // workspace layout (~620 MB total)
  char* ws = (char*)d_ws;
  size_t off = 0;
  auto alloc = [&](size_t bytes) -> char* {
    char* p = ws + off; off += (bytes + 255) & ~(size_t)255; return p;
  };
  bf16_t* src_bf  = (bf16_t*)alloc((size_t)NT * D_ * 2);
  bf16_t* w_in_bf = (bf16_t*)alloc((size_t)3 * D_ * D_ * 2);
  bf16_t* w_out_bf= (bf16_t*)alloc((size_t)D_ * D_ * 2);
  bf16_t* qkv_bf  = (bf16_t*)alloc((size_t)NT * 3 * D_ * 2);
  bf16_t* vT      = (bf16_t*)alloc((size_t)B_ * H_ * HD_ * S_ * 2);
  bf16_t* ctx_bf  = (bf16_t*)alloc((size_t)NT * D_ * 2);
  bf16_t* ao_bf   = (bf16_t*)alloc((size_t)NT * D_ * 2);
  float*  x_f32   = (float*)alloc((size_t)NT * D_ * 4);
  bf16_t* x_bf    = (bf16_t*)alloc((size_t)NT * D_ * 2);
  bf16_t* w1t     = (bf16_t*)alloc((size_t)E_ * D_ * F_ * 2);
  bf16_t* w2t     = (bf16_t*)alloc((size_t)E_ * F_ * D_ * 2);
  bf16_t* xe      = (bf16_t*)alloc((size_t)E_ * CAP * D_ * 2);
  bf16_t* hbuf    = (bf16_t*)alloc((size_t)E_ * CAP * F_ * 2);
  bf16_t* ye      = (bf16_t*)alloc((size_t)E_ * CAP * D_ * 2);
  int*    eidx    = (int*)alloc((size_t)NT * 4);
  int*    pos     = (int*)alloc((size_t)NT * 4);
  float*  gval    = (float*)alloc((size_t)NT * 4);
  int*    cnt     = (int*)alloc((size_t)E_ * 4);

  // 1) dtype conversions / weight transposes
  k_cvt<<<NT * D_ / 8 / 256, 256, 0, stream>>>(src, src_bf, NT * D_ / 8);
  k_cvt<<<3 * D_ * D_ / 8 / 256, 256, 0, stream>>>(in_proj_w, w_in_bf, 3 * D_ * D_ / 8);
  k_cvt<<<D_ * D_ / 8 / 256, 256, 0, stream>>>(out_proj_w, w_out_bf, D_ * D_ / 8);
  k_tcvt<<<dim3(F_ / 64, D_ / 64, E_), 256, 0, stream>>>(w1, w1t, D_, F_, (long)D_ * F_, (long)D_ * F_);
  k_tcvt<<<dim3(D_ / 64, F_ / 64, E_), 256, 0, stream>>>(w2, w2t, F_, D_, (long)F_ * D_, (long)F_ * D_);

  // 2) QKV projection
  k_gemm<0><<<dim3(12, 128, 1), 256, 0, stream>>>(src_bf, w_in_bf, in_proj_b, qkv_bf,
      512, 512, 512, 1536, 0, 0, 0, 0, nullptr, NT);

  // 3) attention
  k_tv<<<dim3(S_ / 64, B_ * H_), 256, 0, stream>>>(qkv_bf, vT);
  k_attn<<<dim3(S_ / 64, B_ * H_), 256, 0, stream>>>(qkv_bf, vT, ctx_bf);
  k_gemm<0><<<dim3(4, 128, 1), 256, 0, stream>>>(ctx_bf, w_out_bf, out_proj_b, ao_bf,
      512, 512, 512, 512, 0, 0, 0, 0, nullptr, NT);
  k_ln_res<<<NT / 4, 256, 0, stream>>>(src, ao_bf, ln1_g, ln1_b, x_f32, x_bf);

  // 4) MoE routing
  k_gate<<<NT / 4 / 4, 256, 0, stream>>>(x_f32, gate_w, eidx, gval);
  hipMemsetAsync(cnt, 0, E_ * 4, stream);
  hipMemsetAsync(xe, 0, (size_t)E_ * CAP * D_ * 2, stream);
  k_route<<<NT / 4, 256, 0, stream>>>(x_bf, eidx, pos, cnt, xe);

  // 5) expert FFN (capacity-aware tile early-exit via cnt)
  k_gemm<1><<<dim3(F_ / 128, CAP / 128, E_), 256, 0, stream>>>(xe, w1t, b1, hbuf,
      512, 512, 512, 2048, (long)CAP * D_, (long)F_ * D_, (long)CAP * F_, F_, cnt, CAP);
  k_gemm<0><<<dim3(D_ / 128, CAP / 128, E_), 256, 0, stream>>>(hbuf, w2t, b2, ye,
      2048, 2048, 2048, 512, (long)CAP * F_, (long)F_ * D_, (long)CAP * D_, D_, cnt, CAP);

  // 6) scatter + residual + LN2 -> out
  k_final<<<NT / 4, 256, 0, stream>>>(x_f32, ye, eidx, pos, gval, ln2_g, ln2_b, (float*)d_out);
}